// Round 12
// baseline (7836.144 us; speedup 1.0000x reference)
//
#include <hip/hip_runtime.h>
#include <math.h>

#define VOCAB 1000
#define EMB   128
#define HID   256
#define G4    1024   // 4*HID
#define BATCH 64
#define SEQT  1024
#define NT    512    // threads: 8 waves, 2 waves/SIMD
#define KVC   23     // register chunks (4 half2 cols each): cols 0..91
#define KLC   9      // LDS tail chunks: cols 92..127

typedef unsigned int u32;
typedef _Float16 f16;
typedef __attribute__((ext_vector_type(2))) _Float16 h2v;
union H2U { u32 u; h2v h; unsigned short s[2]; };

#if defined(__has_builtin)
# if __has_builtin(__builtin_amdgcn_fdot2)
#  define HAVE_FDOT2 1
# endif
#endif
__device__ __forceinline__ float fdot2_(u32 a, u32 b, float c) {
    H2U ua, ub; ua.u = a; ub.u = b;
#ifdef HAVE_FDOT2
    return __builtin_amdgcn_fdot2(ua.h, ub.h, c, false);   // v_dot2_f32_f16
#else
    return c + (float)ua.h.x * (float)ub.h.x + (float)ua.h.y * (float)ub.h.y;
#endif
}

__device__ __forceinline__ float sigmoidf_(float x) {
    return 1.f / (1.f + __expf(-x));
}
__device__ __forceinline__ float tanhf_(float x) {
    return 1.f - 2.f / (__expf(2.f * x) + 1.f);
}

// thread tau -> its two gate rows. Lane-pair mapping: wave w lane l=2m+e
// owns unit u=32w+m; e=0 -> rows (i_u, g_u), e=1 -> rows (f_u, o_u).
__device__ __forceinline__ void rows_of(int tau, int& rA, int& rB, int& u, int& e) {
    const int w = tau >> 6, l = tau & 63;
    e = l & 1;
    u = (w << 5) + (l >> 1);
    rA = e ? (HID + u) : u;                   // f : i
    rB = e ? (3 * HID + u) : (2 * HID + u);   // o : g
}

// ---------------------------------------------------------------------------
// Kernel 1: eproj[v][g] = emb[v] . W_ih[g] + b_ih[g] + b_hh[g]   (fp32, exact)
// ---------------------------------------------------------------------------
__global__ __launch_bounds__(1024) void eproj_kernel(
    const float* __restrict__ emb, const float* __restrict__ W_ih,
    const float* __restrict__ b_ih, const float* __restrict__ b_hh,
    float* __restrict__ eproj)
{
    const int v = blockIdx.x;
    const int g = threadIdx.x;
    __shared__ __align__(16) float x_sh[EMB];
    if (g < EMB / 4) {
        ((float4*)x_sh)[g] = ((const float4*)(emb + (size_t)v * EMB))[g];
    }
    __syncthreads();
    const float4* wrow = (const float4*)(W_ih + (size_t)g * EMB);
    float a0 = 0.f, a1 = 0.f, a2 = 0.f, a3 = 0.f;
#pragma unroll
    for (int e4 = 0; e4 < EMB / 4; e4++) {
        float4 wv = wrow[e4];
        float4 xv = ((const float4*)x_sh)[e4];
        a0 += wv.x * xv.x;
        a1 += wv.y * xv.y;
        a2 += wv.z * xv.z;
        a3 += wv.w * xv.w;
    }
    eproj[(size_t)v * G4 + g] = (a0 + a1) + (a2 + a3) + b_ih[g] + b_hh[g];
}

// ---------------------------------------------------------------------------
// Kernel 2: pack W_hh fp32 -> fp16 half2 uint4 chunks keyed by CONSUMING
// thread: wvq[(q*2+slot)*NT + tau] = rows rA/rB(tau), half2 cols 4q..4q+3.
// Consecutive tau -> consecutive 16B: conflict-free b128 on both sides.
// ---------------------------------------------------------------------------
__global__ __launch_bounds__(NT) void pack_whh(
    const float* __restrict__ Whh, uint4* __restrict__ wvq, uint4* __restrict__ wlq)
{
    const int c   = blockIdx.x;          // chunk 0..(KVC+KLC-1)
    const int tau = threadIdx.x;
    int rA, rB, u, e;
    rows_of(tau, rA, rB, u, e);
    const int rows[2] = { rA, rB };
#pragma unroll
    for (int slot = 0; slot < 2; slot++) {
        const int r = rows[slot];
        const int mc = (c < KVC) ? (4 * c) : (4 * KVC + 4 * (c - KVC));
        H2U q0, q1, q2, q3;
        q0.h.x = (f16)Whh[(size_t)r * HID + 2 * (mc + 0)];
        q0.h.y = (f16)Whh[(size_t)r * HID + 2 * (mc + 0) + 1];
        q1.h.x = (f16)Whh[(size_t)r * HID + 2 * (mc + 1)];
        q1.h.y = (f16)Whh[(size_t)r * HID + 2 * (mc + 1) + 1];
        q2.h.x = (f16)Whh[(size_t)r * HID + 2 * (mc + 2)];
        q2.h.y = (f16)Whh[(size_t)r * HID + 2 * (mc + 2) + 1];
        q3.h.x = (f16)Whh[(size_t)r * HID + 2 * (mc + 3)];
        q3.h.y = (f16)Whh[(size_t)r * HID + 2 * (mc + 3) + 1];
        uint4 pk = { q0.u, q1.u, q2.u, q3.u };
        if (c < KVC) wvq[((size_t)c * 2 + slot) * NT + tau] = pk;
        else         wlq[((size_t)(c - KVC) * 2 + slot) * NT + tau] = pk;
    }
}

// ---------------------------------------------------------------------------
// Kernel 3: single-CU LSTM, latency-scheduled.
// R11 structure (512 thr, lane-pair gates, shfl exchange, 1 barrier/step)
// plus: (a) tail-weight LDS loads hoisted ~1000cyc before use (9 b128 at
// step top, 9 mid-loop) so no lgkmcnt exposure; (b) h-broadcast prefetch
// depth 2; (c) activation split across the lane pair (both exp chains run
// concurrently, shfl moves ACTIVATED values).
// ---------------------------------------------------------------------------
__global__ __launch_bounds__(NT, 2) void lstm_single_cu(
    const int* __restrict__ ids, const int* __restrict__ lens,
    const float* __restrict__ eproj,
    const uint4* __restrict__ wvq, const uint4* __restrict__ wlq,
    float* __restrict__ out)
{
    const int b   = blockIdx.x;
    const int tau = threadIdx.x;
    int rA, rB, u, e;
    rows_of(tau, rA, rB, u, e);

    __shared__ uint4 wl_sh[KLC * 2 * NT];        // 144 KB weight tail
    __shared__ u32   h2_sh[2][HID / 2];          // h as half2, parity x2

    // stage LDS weight tail (b128 both sides, coalesced; 18 uint4/thread)
#pragma unroll
    for (int t = 0; t < (KLC * 2 * NT) / NT; t++)
        wl_sh[t * NT + tau] = wlq[t * NT + tau];
    if (tau < HID / 2) h2_sh[0][tau] = 0u;       // h(0) = 0

    // persistent weights: 2 rows x 92 half2 = 184 regs (AGPR-backed)
    u32 wA[KVC * 4], wB[KVC * 4];
#pragma unroll
    for (int q = 0; q < KVC; q++) {
        uint4 ta = wvq[(q * 2 + 0) * NT + tau];
        uint4 tb = wvq[(q * 2 + 1) * NT + tau];
        wA[4 * q + 0] = ta.x; wA[4 * q + 1] = ta.y;
        wA[4 * q + 2] = ta.z; wA[4 * q + 3] = ta.w;
        wB[4 * q + 0] = tb.x; wB[4 * q + 1] = tb.y;
        wB[4 * q + 2] = tb.z; wB[4 * q + 3] = tb.w;
    }

    const int len = lens[b];                     // >= 1
    const int* idr = ids + (size_t)b * SEQT;
    float c = 0.f, hf = 0.f;

    const float* e0 = eproj + (size_t)idr[0] * G4;
    float xA = e0[rA], xB = e0[rB];

    __syncthreads();

    for (int t = 0; t < len; t++) {
        // prefetch next step's input projections (hidden under dot loops)
        const int nt = (t + 1 < len) ? t + 1 : len - 1;
        const float* en = eproj + (size_t)idr[nt] * G4;
        const float nA = en[rA], nB = en[rB];

        const int p = t & 1;
        const uint4* hb4 = (const uint4*)h2_sh[p];   // 32 b128 broadcasts
        float aA = xA, aB = xB;

        // ---- hoist tail-weight slot-A loads (used ~1000 cyc later) ----
        uint4 tAw[KLC], tBw[KLC];
#pragma unroll
        for (int q = 0; q < KLC; q++)
            tAw[q] = wl_sh[(q * 2 + 0) * NT + tau];

        // ---- register chunks, h prefetch depth 2 ----
        uint4 h0 = hb4[0];
        uint4 h1 = hb4[1];
#pragma unroll
        for (int q = 0; q < KVC; q++) {
            const uint4 hn = hb4[(q + 2 < KVC + KLC) ? q + 2 : KVC + KLC - 1];
            aA = fdot2_(wA[4 * q + 0], h0.x, aA);
            aB = fdot2_(wB[4 * q + 0], h0.x, aB);
            aA = fdot2_(wA[4 * q + 1], h0.y, aA);
            aB = fdot2_(wB[4 * q + 1], h0.y, aB);
            aA = fdot2_(wA[4 * q + 2], h0.z, aA);
            aB = fdot2_(wB[4 * q + 2], h0.z, aB);
            aA = fdot2_(wA[4 * q + 3], h0.w, aA);
            aB = fdot2_(wB[4 * q + 3], h0.w, aB);
            h0 = h1; h1 = hn;
            if (q == 11) {           // mid-loop hoist of slot-B tail loads
#pragma unroll
                for (int z = 0; z < KLC; z++)
                    tBw[z] = wl_sh[(z * 2 + 1) * NT + tau];
            }
        }
        // ---- LDS tail: weights already in registers, zero DS exposure ----
#pragma unroll
        for (int q = 0; q < KLC; q++) {
            const uint4 hn = hb4[(KVC + q + 2 < KVC + KLC) ? KVC + q + 2
                                                           : KVC + KLC - 1];
            aA = fdot2_(tAw[q].x, h0.x, aA);
            aB = fdot2_(tBw[q].x, h0.x, aB);
            aA = fdot2_(tAw[q].y, h0.y, aA);
            aB = fdot2_(tBw[q].y, h0.y, aB);
            aA = fdot2_(tAw[q].z, h0.z, aA);
            aB = fdot2_(tBw[q].z, h0.z, aB);
            aA = fdot2_(tAw[q].w, h0.w, aA);
            aB = fdot2_(tBw[q].w, h0.w, aB);
            h0 = h1; h1 = hn;
        }

        // ---- split activation: both lanes activate their own sums ----
        const float actA = sigmoidf_(aA);                       // ig : fg
        const float actB = e ? sigmoidf_(aB) : tanhf_(aB);      // og : gg
        const float pA = __shfl_xor(actA, 1);   // even lane receives fg
        const float pB = __shfl_xor(actB, 1);   // even lane receives og

        if (e == 0) {                // unit owner: short serial chain
            c = pA * c + actA * actB;            // fg*c + ig*gg
            hf = pB * tanhf_(c);                 // og*tanh(c)
            H2U hv; hv.h.x = (f16)hf; hv.h.y = (f16)0.f;
            ((unsigned short*)h2_sh[p ^ 1])[u] = hv.s[0];
        }
        xA = nA; xB = nB;
        __syncthreads();             // the ONE barrier per step
    }

    if (e == 0) out[(size_t)b * HID + u] = hf;
}

// ---------------------------------------------------------------------------
// Fallback (ws too small): correct-but-slow single-block fp32 version.
// ---------------------------------------------------------------------------
__global__ __launch_bounds__(1024, 1) void lstm_fallback(
    const int* __restrict__ ids, const int* __restrict__ lens,
    const float* __restrict__ emb, const float* __restrict__ W_ih,
    const float* __restrict__ b_ih, const float* __restrict__ b_hh,
    const float* __restrict__ W_hh, float* __restrict__ out)
{
    const int b = blockIdx.x;
    const int t = threadIdx.x;

    __shared__ __align__(16) float h_sh[HID];
    __shared__ __align__(16) float c_sh[HID];
    __shared__ __align__(16) float gates[G4];
    __shared__ __align__(16) float x_sh[EMB];

    float wih[EMB];
    {
        const float4* wr = (const float4*)(W_ih + (size_t)t * EMB);
#pragma unroll
        for (int e4 = 0; e4 < EMB / 4; e4++) {
            float4 wv = wr[e4];
            wih[4 * e4 + 0] = wv.x;
            wih[4 * e4 + 1] = wv.y;
            wih[4 * e4 + 2] = wv.z;
            wih[4 * e4 + 3] = wv.w;
        }
    }
    float bias = b_ih[t] + b_hh[t];

    const int len = lens[b];
    const int* ids_row = ids + (size_t)b * SEQT;
    if (t < HID) { h_sh[t] = 0.f; c_sh[t] = 0.f; }
    __syncthreads();

    for (int step = 0; step < len; step++) {
        int id = ids_row[step];
        if (t < EMB / 4) {
            ((float4*)x_sh)[t] = ((const float4*)(emb + (size_t)id * EMB))[t];
        }
        __syncthreads();
        float a0 = bias, a1 = 0.f, a2 = 0.f, a3 = 0.f;
#pragma unroll
        for (int e4 = 0; e4 < EMB / 4; e4++) {
            float4 xv = ((const float4*)x_sh)[e4];
            a0 += wih[4 * e4 + 0] * xv.x;
            a1 += wih[4 * e4 + 1] * xv.y;
            a2 += wih[4 * e4 + 2] * xv.z;
            a3 += wih[4 * e4 + 3] * xv.w;
        }
        float acc = (a0 + a1) + (a2 + a3);

        const float* wrow = W_hh + (size_t)t * HID;
        a0 = acc; a1 = 0.f; a2 = 0.f; a3 = 0.f;
        for (int k4 = 0; k4 < HID / 4; k4++) {
            float4 hv = ((const float4*)h_sh)[k4];
            float4 wv = ((const float4*)wrow)[k4];
            a0 += wv.x * hv.x;
            a1 += wv.y * hv.y;
            a2 += wv.z * hv.z;
            a3 += wv.w * hv.w;
        }
        gates[t] = (a0 + a1) + (a2 + a3);
        __syncthreads();

        if (t < HID) {
            float ig = sigmoidf_(gates[t]);
            float fg = sigmoidf_(gates[HID + t]);
            float gg = tanhf_(gates[2 * HID + t]);
            float og = sigmoidf_(gates[3 * HID + t]);
            float cc = fg * c_sh[t] + ig * gg;
            c_sh[t] = cc;
            h_sh[t] = og * tanhf_(cc);
        }
        __syncthreads();
    }
    if (t < HID) out[(size_t)b * HID + t] = h_sh[t];
}

extern "C" void kernel_launch(void* const* d_in, const int* in_sizes, int n_in,
                              void* d_out, int out_size, void* d_ws, size_t ws_size,
                              hipStream_t stream) {
    const int*   ids  = (const int*)d_in[0];
    const int*   lens = (const int*)d_in[1];
    const float* emb  = (const float*)d_in[2];
    const float* Wih  = (const float*)d_in[3];
    const float* Whh  = (const float*)d_in[4];
    const float* bih  = (const float*)d_in[5];
    const float* bhh  = (const float*)d_in[6];
    float* out = (float*)d_out;

    // ws layout: eproj 4 MB | wvq 368 KB | wlq 144 KB
    const size_t ep_bytes = (size_t)VOCAB * G4 * sizeof(float);
    const size_t wv_off   = ep_bytes;
    const size_t wv_bytes = (size_t)KVC * 2 * NT * sizeof(uint4);
    const size_t wl_off   = wv_off + wv_bytes;
    const size_t wl_bytes = (size_t)KLC * 2 * NT * sizeof(uint4);

    if (ws_size >= wl_off + wl_bytes) {
        float* eproj = (float*)d_ws;
        uint4* wvp   = (uint4*)((char*)d_ws + wv_off);
        uint4* wlp   = (uint4*)((char*)d_ws + wl_off);
        eproj_kernel<<<VOCAB, 1024, 0, stream>>>(emb, Wih, bih, bhh, eproj);
        pack_whh<<<KVC + KLC, NT, 0, stream>>>(Whh, wvp, wlp);
        lstm_single_cu<<<BATCH, NT, 0, stream>>>(ids, lens, eproj, wvp, wlp, out);
    } else {
        lstm_fallback<<<BATCH, 1024, 0, stream>>>(
            ids, lens, emb, Wih, bih, bhh, Whh, out);
    }
}

// Round 13
// 1770.434 us; speedup vs baseline: 4.4261x; 4.4261x over previous
//
#include <hip/hip_runtime.h>
#include <math.h>

#define VOCAB 1000
#define EMB   128
#define HID   256
#define G4    1024   // 4*HID
#define BATCH 64
#define SEQT  1024
#define KV    92     // half2 cols in VGPRs  (k in [0,184))
#define KL    36     // half2 cols in LDS    (k in [184,256)), 9 b128 chunks

typedef unsigned int u32;
typedef _Float16 f16;
typedef __attribute__((ext_vector_type(2))) _Float16 h2v;
union H2U { u32 u; h2v h; unsigned short s[2]; };

#if defined(__has_builtin)
# if __has_builtin(__builtin_amdgcn_fdot2)
#  define HAVE_FDOT2 1
# endif
#endif
__device__ __forceinline__ float fdot2_(u32 a, u32 b, float c) {
    H2U ua, ub; ua.u = a; ub.u = b;
#ifdef HAVE_FDOT2
    return __builtin_amdgcn_fdot2(ua.h, ub.h, c, false);   // v_dot2_f32_f16
#else
    return c + (float)ua.h.x * (float)ub.h.x + (float)ua.h.y * (float)ub.h.y;
#endif
}

__device__ __forceinline__ float sigmoidf_(float x) {
    return 1.f / (1.f + __expf(-x));
}
__device__ __forceinline__ float tanhf_(float x) {
    return 1.f - 2.f / (__expf(2.f * x) + 1.f);
}

// ---------------------------------------------------------------------------
// Kernel 1: eproj[v][g] = emb[v] . W_ih[g] + b_ih[g] + b_hh[g]   (fp32, exact)
// ---------------------------------------------------------------------------
__global__ __launch_bounds__(1024) void eproj_kernel(
    const float* __restrict__ emb, const float* __restrict__ W_ih,
    const float* __restrict__ b_ih, const float* __restrict__ b_hh,
    float* __restrict__ eproj)
{
    const int v = blockIdx.x;
    const int g = threadIdx.x;
    __shared__ __align__(16) float x_sh[EMB];
    if (g < EMB / 4) {
        ((float4*)x_sh)[g] = ((const float4*)(emb + (size_t)v * EMB))[g];
    }
    __syncthreads();
    const float4* wrow = (const float4*)(W_ih + (size_t)g * EMB);
    float a0 = 0.f, a1 = 0.f, a2 = 0.f, a3 = 0.f;
#pragma unroll
    for (int e4 = 0; e4 < EMB / 4; e4++) {
        float4 wv = wrow[e4];
        float4 xv = ((const float4*)x_sh)[e4];
        a0 += wv.x * xv.x;
        a1 += wv.y * xv.y;
        a2 += wv.z * xv.z;
        a3 += wv.w * xv.w;
    }
    eproj[(size_t)v * G4 + g] = (a0 + a1) + (a2 + a3) + b_ih[g] + b_hh[g];
}

// ---------------------------------------------------------------------------
// Kernel 2: pack W_hh fp32 -> fp16 half2 into two [chunk][row][4] u32 arrays:
// wvq (cols 0..183, 23 chunks) register part, wlq (cols 184..255, 9 chunks)
// LDS part. [chunk][row][4] makes both global loads and LDS b128 reads
// lane-consecutive (canonical conflict-free float4 pattern).
// ---------------------------------------------------------------------------
__global__ __launch_bounds__(128) void pack_whh(
    const float* __restrict__ Whh, u32* __restrict__ wv, u32* __restrict__ wl)
{
    const int r = blockIdx.x;        // row 0..1023
    const int m = threadIdx.x;       // half2 col 0..127
    H2U u;
    u.h.x = (f16)Whh[(size_t)r * HID + 2 * m];
    u.h.y = (f16)Whh[(size_t)r * HID + 2 * m + 1];
    if (m < KV) {
        wv[(size_t)(m >> 2) * (G4 * 4) + r * 4 + (m & 3)] = u.u;
    } else {
        const int mm = m - KV;
        wl[(size_t)(mm >> 2) * (G4 * 4) + r * 4 + (mm & 3)] = u.u;
    }
}

// ---------------------------------------------------------------------------
// Kernel 3: single-CU LSTM (R10 configuration — best measured: 1645 us).
// One block (512 thr, 8 waves, 2 waves/SIMD -> 256 unified regs/wave) per
// batch element. Thread tau owns gate rows tau (i or f) and 512+tau (g or o):
// 2 x 92 half2 = 184 persistent regs (AGPR-backed; 120 arch + 128 acc = 248
// of 256 — AT the allocation cliff, do not add live state: R9/R12 both
// spilled from exactly this). Weight tail (36 half2 cols) in LDS, lane-
// consecutive b128, read one chunk ahead. Unit j's activation: thread j has
// (i,g); thread 256+j passes (f,o) sums via a 2 KB LDS bounce. Zero
// cross-CU traffic (FETCH 17.7 MB, WRITE 64 KB signature).
// ---------------------------------------------------------------------------
__global__ __launch_bounds__(512, 2) void lstm_single_cu(
    const int* __restrict__ ids, const int* __restrict__ lens,
    const float* __restrict__ eproj,
    const u32* __restrict__ wvq, const u32* __restrict__ wlq,
    float* __restrict__ out)
{
    const int b   = blockIdx.x;
    const int tau = threadIdx.x;                 // 0..511
    const int rA  = tau;                         // gate i (tau<256) / f
    const int rB  = 512 + tau;                   // gate g (tau<256) / o

    __shared__ u32 wl_sh[KL / 4 * G4 * 4];       // 9 chunks x 1024 rows x 16B
    __shared__ u32 h2_sh[2][HID / 2];            // h as half2, parity x2
    __shared__ float gs_f[HID], gs_o[HID];       // f,o gate-sum bounce

    // stage LDS weight tail (b128 both sides, coalesced)
    {
        const uint4* src = (const uint4*)wlq;
        uint4*       dst = (uint4*)wl_sh;
#pragma unroll
        for (int t = 0; t < (KL / 4) * G4 / 512; t++)   // 18 iters
            dst[t * 512 + tau] = src[t * 512 + tau];
    }
    if (tau < HID / 2) h2_sh[0][tau] = 0u;       // h(0) = 0

    // persistent VGPR weights: 2 rows x 92 half2 = 184 regs
    u32 wA[KV], wB[KV];
#pragma unroll
    for (int q = 0; q < KV / 4; q++) {
        uint4 ta = ((const uint4*)wvq)[q * G4 + rA];
        uint4 tb = ((const uint4*)wvq)[q * G4 + rB];
        wA[4 * q + 0] = ta.x; wA[4 * q + 1] = ta.y;
        wA[4 * q + 2] = ta.z; wA[4 * q + 3] = ta.w;
        wB[4 * q + 0] = tb.x; wB[4 * q + 1] = tb.y;
        wB[4 * q + 2] = tb.z; wB[4 * q + 3] = tb.w;
    }

    const int len = lens[b];                     // >= 1
    const int* idr = ids + (size_t)b * SEQT;
    float c = 0.f, hf = 0.f;

    const float* e0 = eproj + (size_t)idr[0] * G4;
    float xA = e0[rA], xB = e0[rB];

    __syncthreads();

    for (int t = 0; t < len; t++) {
        // prefetch next step's input projections (hidden under dot loops)
        const int nt = (t + 1 < len) ? t + 1 : len - 1;
        const float* en = eproj + (size_t)idr[nt] * G4;
        const float nA = en[rA], nB = en[rB];

        const int p = t & 1;
        const uint4* hb4 = (const uint4*)h2_sh[p];   // 32 b128 broadcasts
        float aA = xA, aB = xB;

        // register cols 0..91
#pragma unroll
        for (int q = 0; q < KV / 4; q++) {
            uint4 h4 = hb4[q];
            aA = fdot2_(wA[4 * q + 0], h4.x, aA);
            aB = fdot2_(wB[4 * q + 0], h4.x, aB);
            aA = fdot2_(wA[4 * q + 1], h4.y, aA);
            aB = fdot2_(wB[4 * q + 1], h4.y, aB);
            aA = fdot2_(wA[4 * q + 2], h4.z, aA);
            aB = fdot2_(wB[4 * q + 2], h4.z, aB);
            aA = fdot2_(wA[4 * q + 3], h4.w, aA);
            aB = fdot2_(wB[4 * q + 3], h4.w, aB);
        }
        // LDS tail cols 92..127 (lane-consecutive b128, conflict-free)
#pragma unroll
        for (int q = 0; q < KL / 4; q++) {
            uint4 h4 = hb4[KV / 4 + q];
            uint4 tA = ((const uint4*)wl_sh)[q * G4 + rA];
            uint4 tB = ((const uint4*)wl_sh)[q * G4 + rB];
            aA = fdot2_(tA.x, h4.x, aA);
            aB = fdot2_(tB.x, h4.x, aB);
            aA = fdot2_(tA.y, h4.y, aA);
            aB = fdot2_(tB.y, h4.y, aB);
            aA = fdot2_(tA.z, h4.z, aA);
            aB = fdot2_(tB.z, h4.z, aB);
            aA = fdot2_(tA.w, h4.w, aA);
            aB = fdot2_(tB.w, h4.w, aB);
        }

        if (tau >= HID) {            // rows f,o: pass sums to unit owner
            gs_f[tau - HID] = aA;
            gs_o[tau - HID] = aB;
        }
        __syncthreads();             // barrier A: sums visible

        if (tau < HID) {             // unit owner: i,g local + f,o from LDS
            float ig = sigmoidf_(aA);
            float gg = tanhf_(aB);
            float fg = sigmoidf_(gs_f[tau]);
            float og = sigmoidf_(gs_o[tau]);
            c = fg * c + ig * gg;
            hf = og * tanhf_(c);
            H2U hv; hv.h.x = (f16)hf; hv.h.y = (f16)0.f;
            ((unsigned short*)h2_sh[p ^ 1])[tau] = hv.s[0];
        }
        xA = nA; xB = nB;
        __syncthreads();             // barrier B: h(t+1) published
    }

    if (tau < HID) out[(size_t)b * HID + tau] = hf;
}

// ---------------------------------------------------------------------------
// Fallback (ws too small): correct-but-slow single-block fp32 version.
// ---------------------------------------------------------------------------
__global__ __launch_bounds__(1024, 1) void lstm_fallback(
    const int* __restrict__ ids, const int* __restrict__ lens,
    const float* __restrict__ emb, const float* __restrict__ W_ih,
    const float* __restrict__ b_ih, const float* __restrict__ b_hh,
    const float* __restrict__ W_hh, float* __restrict__ out)
{
    const int b = blockIdx.x;
    const int t = threadIdx.x;

    __shared__ __align__(16) float h_sh[HID];
    __shared__ __align__(16) float c_sh[HID];
    __shared__ __align__(16) float gates[G4];
    __shared__ __align__(16) float x_sh[EMB];

    float wih[EMB];
    {
        const float4* wr = (const float4*)(W_ih + (size_t)t * EMB);
#pragma unroll
        for (int e4 = 0; e4 < EMB / 4; e4++) {
            float4 wv = wr[e4];
            wih[4 * e4 + 0] = wv.x;
            wih[4 * e4 + 1] = wv.y;
            wih[4 * e4 + 2] = wv.z;
            wih[4 * e4 + 3] = wv.w;
        }
    }
    float bias = b_ih[t] + b_hh[t];

    const int len = lens[b];
    const int* ids_row = ids + (size_t)b * SEQT;
    if (t < HID) { h_sh[t] = 0.f; c_sh[t] = 0.f; }
    __syncthreads();

    for (int step = 0; step < len; step++) {
        int id = ids_row[step];
        if (t < EMB / 4) {
            ((float4*)x_sh)[t] = ((const float4*)(emb + (size_t)id * EMB))[t];
        }
        __syncthreads();
        float a0 = bias, a1 = 0.f, a2 = 0.f, a3 = 0.f;
#pragma unroll
        for (int e4 = 0; e4 < EMB / 4; e4++) {
            float4 xv = ((const float4*)x_sh)[e4];
            a0 += wih[4 * e4 + 0] * xv.x;
            a1 += wih[4 * e4 + 1] * xv.y;
            a2 += wih[4 * e4 + 2] * xv.z;
            a3 += wih[4 * e4 + 3] * xv.w;
        }
        float acc = (a0 + a1) + (a2 + a3);

        const float* wrow = W_hh + (size_t)t * HID;
        a0 = acc; a1 = 0.f; a2 = 0.f; a3 = 0.f;
        for (int k4 = 0; k4 < HID / 4; k4++) {
            float4 hv = ((const float4*)h_sh)[k4];
            float4 wv = ((const float4*)wrow)[k4];
            a0 += wv.x * hv.x;
            a1 += wv.y * hv.y;
            a2 += wv.z * hv.z;
            a3 += wv.w * hv.w;
        }
        gates[t] = (a0 + a1) + (a2 + a3);
        __syncthreads();

        if (t < HID) {
            float ig = sigmoidf_(gates[t]);
            float fg = sigmoidf_(gates[HID + t]);
            float gg = tanhf_(gates[2 * HID + t]);
            float og = sigmoidf_(gates[3 * HID + t]);
            float cc = fg * c_sh[t] + ig * gg;
            c_sh[t] = cc;
            h_sh[t] = og * tanhf_(cc);
        }
        __syncthreads();
    }
    if (t < HID) out[(size_t)b * HID + t] = h_sh[t];
}

extern "C" void kernel_launch(void* const* d_in, const int* in_sizes, int n_in,
                              void* d_out, int out_size, void* d_ws, size_t ws_size,
                              hipStream_t stream) {
    const int*   ids  = (const int*)d_in[0];
    const int*   lens = (const int*)d_in[1];
    const float* emb  = (const float*)d_in[2];
    const float* Wih  = (const float*)d_in[3];
    const float* Whh  = (const float*)d_in[4];
    const float* bih  = (const float*)d_in[5];
    const float* bhh  = (const float*)d_in[6];
    float* out = (float*)d_out;

    // ws layout: eproj 4 MB | wvq 368 KB | wlq 144 KB
    const size_t ep_bytes = (size_t)VOCAB * G4 * sizeof(float);
    const size_t wv_off   = ep_bytes;
    const size_t wv_bytes = (size_t)(KV / 4) * G4 * 4 * sizeof(u32);
    const size_t wl_off   = wv_off + wv_bytes;
    const size_t wl_bytes = (size_t)(KL / 4) * G4 * 4 * sizeof(u32);

    if (ws_size >= wl_off + wl_bytes) {
        float* eproj = (float*)d_ws;
        u32*   wvp   = (u32*)((char*)d_ws + wv_off);
        u32*   wlp   = (u32*)((char*)d_ws + wl_off);
        eproj_kernel<<<VOCAB, 1024, 0, stream>>>(emb, Wih, bih, bhh, eproj);
        pack_whh<<<G4, 128, 0, stream>>>(Whh, wvp, wlp);
        lstm_single_cu<<<BATCH, 512, 0, stream>>>(ids, lens, eproj, wvp, wlp, out);
    } else {
        lstm_fallback<<<BATCH, 1024, 0, stream>>>(
            ids, lens, emb, Wih, bih, bhh, Whh, out);
    }
}